// Round 6
// baseline (237.580 us; speedup 1.0000x reference)
//
#include <hip/hip_runtime.h>
#include <hip/hip_bf16.h>
#include <math.h>

// ---------------- constants ----------------
#define SEQ_LEN 8
#define D_IN 2048
#define D_OUT 1152
#define WAY 5
#define SHOT 5
#define N_SUPPORT 25
#define N_Q 100
#define N_SEQ 125
#define N_ROWS 1000        // N_SEQ * SEQ_LEN
#define T_LEN 56
#define KS_LEN 280         // SHOT * T_LEN
#define KS_PAD 288         // padded (16- and 32-multiple)
#define NCOLS 6912         // 6 * D_OUT
#define MQT 5600           // N_Q * T_LEN
#define DPC 18             // 9 col-tiles x 2 waves, proto dist partials

typedef __attribute__((ext_vector_type(4))) float f32x4;
typedef __attribute__((ext_vector_type(8))) short bf16x8;

__constant__ int TUP[T_LEN][3] = {
  {0,1,2},{0,1,3},{0,1,4},{0,1,5},{0,1,6},{0,1,7},{0,2,3},{0,2,4},{0,2,5},{0,2,6},
  {0,2,7},{0,3,4},{0,3,5},{0,3,6},{0,3,7},{0,4,5},{0,4,6},{0,4,7},{0,5,6},{0,5,7},
  {0,6,7},{1,2,3},{1,2,4},{1,2,5},{1,2,6},{1,2,7},{1,3,4},{1,3,5},{1,3,6},{1,3,7},
  {1,4,5},{1,4,6},{1,4,7},{1,5,6},{1,5,7},{1,6,7},{2,3,4},{2,3,5},{2,3,6},{2,3,7},
  {2,4,5},{2,4,6},{2,4,7},{2,5,6},{2,5,7},{2,6,7},{3,4,5},{3,4,6},{3,4,7},{3,5,6},
  {3,5,7},{3,6,7},{4,5,6},{4,5,7},{4,6,7},{5,6,7}
};

__device__ __forceinline__ ushort f2bf(float f) {
  union { float f; unsigned u; } v; v.f = f;
  unsigned r = v.u + 0x7FFFu + ((v.u >> 16) & 1u);   // RNE
  return (ushort)(r >> 16);
}
__device__ __forceinline__ float bf2f(ushort u) {
  union { unsigned u; float f; } v; v.u = ((unsigned)u) << 16;
  return v.f;
}
__device__ __forceinline__ void gload16(const void* g, const void* l) {
  __builtin_amdgcn_global_load_lds(
      (const __attribute__((address_space(1))) unsigned int*)g,
      (__attribute__((address_space(3))) unsigned int*)l, 16, 0, 0);
}

// ---------------- kernel 0: Xbf = (input + PE) as bf16 ----------------
__global__ __launch_bounds__(256) void pe_add(const float* __restrict__ sup,
                                              const float* __restrict__ que,
                                              ushort* __restrict__ X) {
  int idx = blockIdx.x * 256 + threadIdx.x;
  if (idx >= N_ROWS * D_IN) return;
  int d = idx & (D_IN - 1);
  int r = idx >> 11;
  int i = r & 7;
  int h2 = d & ~1;
  float freq = expf((float)h2 * (-9.210340371976184f / (float)D_IN)); // ln(10000)
  float ang = (float)i * freq;
  float pe = ((d & 1) ? cosf(ang) : sinf(ang)) * 0.1f;
  float src = (r < N_SUPPORT * SEQ_LEN) ? sup[idx] : que[idx - N_SUPPORT * SEQ_LEN * D_IN];
  X[idx] = f2bf(src + pe);
}

// ---------------- kernel 1: WT[b*1152+n][k] = W_b[k][n] (bf16) -----------
__global__ __launch_bounds__(256) void wtrans(const float* __restrict__ kw,
                                              const float* __restrict__ vw,
                                              ushort* __restrict__ WT) {
  __shared__ float tile[64][65];
  int bx = blockIdx.x;              // 108 n-tiles (6 b-blocks x 18)
  int by = blockIdx.y;              // 32 k-tiles
  int b = bx / 18;
  int n0 = (bx % 18) * 64;
  int k0 = by * 64;
  const float* src = ((b & 1) ? vw : kw) + (size_t)(b >> 1) * D_IN * D_OUT;
  int tid = threadIdx.x;
#pragma unroll
  for (int it = 0; it < 4; ++it) {
    int lin4 = it * 256 + tid;            // 1024 float4 total
    int kk = lin4 >> 4;
    int n4 = (lin4 & 15) * 4;
    float4 v = *(const float4*)(src + (size_t)(k0 + kk) * D_OUT + n0 + n4);
    tile[kk][n4 + 0] = v.x; tile[kk][n4 + 1] = v.y;
    tile[kk][n4 + 2] = v.z; tile[kk][n4 + 3] = v.w;
  }
  __syncthreads();
#pragma unroll
  for (int it = 0; it < 4; ++it) {
    int lin = it * 1024 + tid * 4;        // 4096 elems, 4 k per thread
    int nn = lin >> 6, kk = lin & 63;
    ushort4 o;
    o.x = f2bf(tile[kk + 0][nn]); o.y = f2bf(tile[kk + 1][nn]);
    o.z = f2bf(tile[kk + 2][nn]); o.w = f2bf(tile[kk + 3][nn]);
    *(ushort4*)&WT[((size_t)(b * D_OUT + n0 + nn)) * D_IN + k0 + kk] = o;
  }
}

// ---------------- generic bt-form MFMA GEMM (m97 structure) --------------
// 128 x NT tile, BK=32, 4 waves 2x2 (wave covers 64 x NT/2).
// EPI 0: C=A*BT^T. EPI 1: C*alpha. EPI 2: proto + (qv-proto)^2 partials.
template<int EPI, int NT>
__global__ __launch_bounds__(256) void gemm_bt(
    const ushort* __restrict__ A, const ushort* __restrict__ BT,
    float* __restrict__ C,
    const ushort* __restrict__ QV, float* __restrict__ DP,
    int M, int N, int K, int lda, int ldb, int ldc, float alpha,
    long batchA, long batchB, long batchC) {
  constexpr int JF = NT / 32;          // col frags per wave
  constexpr int NCHUNK = 8 + NT / 16;  // 16-row staging chunks (A + B)
  __shared__ ushort As[128][32];
  __shared__ ushort Bs[NT][32];
  int z = blockIdx.z;
  A  += (size_t)z * batchA;
  BT += (size_t)z * batchB;
  if constexpr (EPI < 2) C  += (size_t)z * batchC;
  else                   DP += (size_t)z * batchC;

  int tid = threadIdx.x;
  int wid = tid >> 6, lane = tid & 63;
  int l16 = lane & 15, lk = lane >> 4;
  int wr = wid >> 1, wc = wid & 1;
  int row0 = blockIdx.x * 128, col0 = blockIdx.y * NT;
  int lrow = lane >> 2, lcol = (lane & 3) * 8;

  f32x4 acc[4][JF] = {};
  for (int k0 = 0; k0 < K; k0 += 32) {
    for (int c = wid; c < NCHUNK; c += 4) {       // wave-uniform chunk index
      if (c < 8) {
        int grow = row0 + c * 16 + lrow;
        grow = grow < M ? grow : M - 1;
        gload16(A + (size_t)grow * lda + k0 + lcol, &As[c * 16][0]);
      } else {
        int gcol = col0 + (c - 8) * 16 + lrow;
        gcol = gcol < N ? gcol : N - 1;
        gload16(BT + (size_t)gcol * ldb + k0 + lcol, &Bs[(c - 8) * 16][0]);
      }
    }
    __syncthreads();
    bf16x8 af[4], bv[JF];
#pragma unroll
    for (int m = 0; m < 4; ++m) af[m] = *(const bf16x8*)&As[wr * 64 + m * 16 + l16][lk * 8];
#pragma unroll
    for (int j = 0; j < JF; ++j) bv[j] = *(const bf16x8*)&Bs[wc * (NT / 2) + j * 16 + l16][lk * 8];
#pragma unroll
    for (int m = 0; m < 4; ++m)
#pragma unroll
      for (int j = 0; j < JF; ++j)
        acc[m][j] = __builtin_amdgcn_mfma_f32_16x16x32_bf16(af[m], bv[j], acc[m][j], 0, 0, 0);
    __syncthreads();
  }

  if constexpr (EPI < 2) {
#pragma unroll
    for (int m = 0; m < 4; ++m)
#pragma unroll
      for (int j = 0; j < JF; ++j) {
        int col = col0 + wc * (NT / 2) + j * 16 + l16;
#pragma unroll
        for (int r = 0; r < 4; ++r) {
          int row = row0 + wr * 64 + m * 16 + lk * 4 + r;
          if (row < M && col < N)
            C[(size_t)row * ldc + col] = (EPI == 1) ? acc[m][j][r] * alpha : acc[m][j][r];
        }
      }
  } else {
    float sq[4][4] = {};
#pragma unroll
    for (int m = 0; m < 4; ++m)
#pragma unroll
      for (int j = 0; j < JF; ++j) {
        int col = col0 + wc * (NT / 2) + j * 16 + l16;   // N=1152 exact
#pragma unroll
        for (int r = 0; r < 4; ++r) {
          int row = row0 + wr * 64 + m * 16 + lk * 4 + r;
          if (row < M) {
            float qvv = bf2f(QV[(size_t)row * D_OUT + col]);
            float d = qvv - acc[m][j][r];
            sq[m][r] += d * d;
          }
        }
      }
#pragma unroll
    for (int m = 0; m < 4; ++m)
#pragma unroll
      for (int r = 0; r < 4; ++r) {
        sq[m][r] += __shfl_xor(sq[m][r], 1);
        sq[m][r] += __shfl_xor(sq[m][r], 2);
        sq[m][r] += __shfl_xor(sq[m][r], 4);
        sq[m][r] += __shfl_xor(sq[m][r], 8);
      }
    if (l16 == 0) {
#pragma unroll
      for (int m = 0; m < 4; ++m)
#pragma unroll
        for (int r = 0; r < 4; ++r) {
          int row = row0 + wr * 64 + m * 16 + lk * 4 + r;
          if (row < M) DP[(size_t)row * DPC + blockIdx.y * 2 + wc] = sq[m][r];
        }
    }
  }
}

// ---------------- kernel 2: tuple-combine + bias + LayerNorm(K) -----------
__global__ __launch_bounds__(256) void combine_ln(const float* __restrict__ G,
                                                  const float* __restrict__ kb,
                                                  const float* __restrict__ vb,
                                                  const float* __restrict__ lng,
                                                  const float* __restrict__ lnb,
                                                  ushort* __restrict__ skbf,
                                                  ushort* __restrict__ qkbf,
                                                  ushort* __restrict__ sv,
                                                  ushort* __restrict__ qvbf) {
  int t = blockIdx.x;   // 0..55
  int n = blockIdx.y;   // 0..124
  const float* g0 = G + (size_t)(n * 8 + TUP[t][0]) * NCOLS;
  const float* g1 = G + (size_t)(n * 8 + TUP[t][1]) * NCOLS + 2 * D_OUT;
  const float* g2 = G + (size_t)(n * 8 + TUP[t][2]) * NCOLS + 4 * D_OUT;
  __shared__ float kbuf[D_OUT];
  __shared__ float red1[256], red2[256];
  int tid = threadIdx.x;
  bool isq = (n >= N_SUPPORT);
  int c = n / SHOT, s = n % SHOT;
  ushort* vout = isq ? qvbf + ((size_t)(n - N_SUPPORT) * T_LEN + t) * D_OUT
                     : sv + ((size_t)c * KS_PAD + s * T_LEN + t) * D_OUT;
  float s1 = 0.f, s2 = 0.f;
  for (int d4 = tid; d4 < D_OUT / 4; d4 += 256) {
    int d = d4 * 4;
    float4 a = *(const float4*)(g0 + d);
    float4 b = *(const float4*)(g0 + D_OUT + d);
    float4 c1 = *(const float4*)(g1 + d);
    float4 c2 = *(const float4*)(g1 + D_OUT + d);
    float4 e1 = *(const float4*)(g2 + d);
    float4 e2 = *(const float4*)(g2 + D_OUT + d);
    float4 kb4 = *(const float4*)(kb + d);
    float4 vb4 = *(const float4*)(vb + d);
    float kx = a.x + c1.x + e1.x + kb4.x, ky = a.y + c1.y + e1.y + kb4.y;
    float kz = a.z + c1.z + e1.z + kb4.z, kw = a.w + c1.w + e1.w + kb4.w;
    float vx = b.x + c2.x + e2.x + vb4.x, vy = b.y + c2.y + e2.y + vb4.y;
    float vz = b.z + c2.z + e2.z + vb4.z, vw = b.w + c2.w + e2.w + vb4.w;
    *(float4*)(kbuf + d) = make_float4(kx, ky, kz, kw);
    ushort4 vv; vv.x = f2bf(vx); vv.y = f2bf(vy); vv.z = f2bf(vz); vv.w = f2bf(vw);
    *(ushort4*)(vout + d) = vv;
    s1 += kx + ky + kz + kw;
    s2 += kx * kx + ky * ky + kz * kz + kw * kw;
  }
  red1[tid] = s1; red2[tid] = s2;
  __syncthreads();
  for (int sft = 128; sft > 0; sft >>= 1) {
    if (tid < sft) { red1[tid] += red1[tid + sft]; red2[tid] += red2[tid + sft]; }
    __syncthreads();
  }
  float mu = red1[0] * (1.0f / D_OUT);
  float var = red2[0] * (1.0f / D_OUT) - mu * mu;
  float rs = rsqrtf(var + 1e-5f);
  ushort* kout = isq ? qkbf + ((size_t)(n - N_SUPPORT) * T_LEN + t) * D_OUT
                     : skbf + ((size_t)c * KS_PAD + s * T_LEN + t) * D_OUT;
  for (int d4 = tid; d4 < D_OUT / 4; d4 += 256) {
    int d = d4 * 4;
    float4 kv = *(const float4*)(kbuf + d);
    float4 g4 = *(const float4*)(lng + d);
    float4 b4 = *(const float4*)(lnb + d);
    ushort4 o;
    o.x = f2bf((kv.x - mu) * rs * g4.x + b4.x);
    o.y = f2bf((kv.y - mu) * rs * g4.y + b4.y);
    o.z = f2bf((kv.z - mu) * rs * g4.z + b4.z);
    o.w = f2bf((kv.w - mu) * rs * g4.w + b4.w);
    *(ushort4*)(kout + d) = o;
  }
}

// ---------------- kernel 2b: svT[c][d][ks] = sv[c][ks][d], zero pad -------
__global__ __launch_bounds__(256) void svtrans(const ushort* __restrict__ sv,
                                               ushort* __restrict__ svT) {
  __shared__ ushort tile[32][65];
  int c = blockIdx.z;
  int d0 = blockIdx.x * 64;   // 18 tiles
  int k0 = blockIdx.y * 32;   // 9 tiles
  const ushort* src = sv + (size_t)c * KS_PAD * D_OUT;
  ushort* dst = svT + (size_t)c * D_OUT * KS_PAD;
  int tid = threadIdx.x;
#pragma unroll
  for (int it = 0; it < 8; ++it) {
    int lin = it * 256 + tid;
    int ks = k0 + (lin >> 6), d = d0 + (lin & 63);
    tile[lin >> 6][lin & 63] = (ks < KS_LEN) ? src[(size_t)ks * D_OUT + d] : (ushort)0;
  }
  __syncthreads();
#pragma unroll
  for (int it = 0; it < 8; ++it) {
    int lin = it * 256 + tid;
    int d = lin >> 5, ks = lin & 31;
    dst[(size_t)(d0 + d) * KS_PAD + k0 + ks] = tile[ks][d];
  }
}

// ---------------- kernel 3: softmax (fp32) + align + sm bf16 -------------
__global__ __launch_bounds__(256) void softmax_align(const float* __restrict__ S,
                                                     ushort* __restrict__ sm,
                                                     float* __restrict__ align_out) {
  __shared__ float pl[4][KS_LEN];
  int wid = threadIdx.x >> 6, lane = threadIdx.x & 63;
  int row = blockIdx.x * 4 + wid;         // 0..27999
  const float* src = S + (size_t)row * KS_PAD;
  float v[5];
  float mx = -1e30f;
#pragma unroll
  for (int j = 0; j < 5; ++j) {
    int ks = lane + j * 64;
    v[j] = (ks < KS_LEN) ? src[ks] : -1e30f;
    mx = fmaxf(mx, v[j]);
  }
#pragma unroll
  for (int m = 32; m > 0; m >>= 1) mx = fmaxf(mx, __shfl_xor(mx, m));
  float sum = 0.f;
  float p[5];
#pragma unroll
  for (int j = 0; j < 5; ++j) {
    int ks = lane + j * 64;
    p[j] = (ks < KS_LEN) ? expf(v[j] - mx) : 0.f;
    sum += p[j];
  }
#pragma unroll
  for (int m = 32; m > 0; m >>= 1) sum += __shfl_xor(sum, m);
  float inv = 1.0f / sum;
  ushort* dst = sm + (size_t)row * KS_PAD;
#pragma unroll
  for (int j = 0; j < 5; ++j) {
    int ks = lane + j * 64;
    if (ks < KS_PAD) dst[ks] = f2bf((ks < KS_LEN) ? p[j] * inv : 0.f);
  }
  int c = row / MQT;
  if (c == WAY - 1) {
#pragma unroll
    for (int j = 0; j < 5; ++j) {
      int ks = lane + j * 64;
      if (ks < KS_LEN) pl[wid][ks] = p[j] * inv;
    }
    __syncthreads();
    if (lane < T_LEN) {
      float a = 0.f;
#pragma unroll
      for (int k = 0; k < SHOT; ++k) a += pl[wid][k * T_LEN + lane];
      int qt = row - (WAY - 1) * MQT;
      align_out[(size_t)(qt / T_LEN) * (T_LEN * T_LEN) + (qt % T_LEN) * T_LEN + lane] = a;
    }
  }
}

// ---------------- kernel 4: logits -----------------------------------
__global__ __launch_bounds__(256) void logits_k(const float* __restrict__ DP,
                                                float* __restrict__ out) {
  __shared__ float red[256];
  int q = blockIdx.x / WAY, c = blockIdx.x % WAY;
  const float* base = DP + ((size_t)c * MQT + q * T_LEN) * DPC;  // 56*18=1008
  int tid = threadIdx.x;
  float s = 0.f;
  for (int i = tid; i < T_LEN * DPC; i += 256) s += base[i];
  red[tid] = s;
  __syncthreads();
  for (int sft = 128; sft > 0; sft >>= 1) {
    if (tid < sft) red[tid] += red[tid + sft];
    __syncthreads();
  }
  if (tid == 0) out[blockIdx.x] = -red[0] * (1.0f / T_LEN);
}

// ---------------- launch ----------------
extern "C" void kernel_launch(void* const* d_in, const int* in_sizes, int n_in,
                              void* d_out, int out_size, void* d_ws, size_t ws_size,
                              hipStream_t stream) {
  const float* sup  = (const float*)d_in[0];
  const float* que  = (const float*)d_in[1];
  const float* k_w  = (const float*)d_in[3];
  const float* k_b  = (const float*)d_in[4];
  const float* v_w  = (const float*)d_in[5];
  const float* v_b  = (const float*)d_in[6];
  const float* ln_g = (const float*)d_in[7];
  const float* ln_b = (const float*)d_in[8];
  float* out = (float*)d_out;

  char* w = (char*)d_ws;
  // Live ranges allow heavy aliasing; footprint kept at 92.5 MB.
  ushort* Xbf  = (ushort*)(w + 0);            //  4,096,000  (dead after proj)
  ushort* WT   = (ushort*)(w + 4096000);      // 28,311,552  (dead after proj)
  float*  G    = (float*)(w + 32407552);      // 27,648,000  (dead after combine)
  ushort* sv   = (ushort*)(w + 0);            //  3,317,760  (alias Xbf; dead after svtrans)
  float*  S    = (float*)(w + 0);             // 32,256,000  (alias; dead after softmax)
  ushort* smbf = (ushort*)(w + 32407552);     // 16,128,000  (alias G)
  float*  DP   = (float*)(w + 0);             //  2,016,000  (alias S after softmax)
  ushort* qkbf = (ushort*)(w + 60055552);     // 12,902,400
  ushort* skbf = (ushort*)(w + 72957952);     //  3,317,760
  ushort* svT  = (ushort*)(w + 76275712);     //  3,317,760
  ushort* qvbf = (ushort*)(w + 79593472);     // 12,902,400 -> end 92,495,872

  const float scale = 0.02946278254943948f; // 1/sqrt(1152)

  pe_add<<<dim3(8000), 256, 0, stream>>>(sup, que, Xbf);
  wtrans<<<dim3(108, 32), 256, 0, stream>>>(k_w, v_w, WT);
  gemm_bt<0, 64><<<dim3(8, 108, 1), 256, 0, stream>>>(
      Xbf, WT, G, nullptr, nullptr,
      N_ROWS, NCOLS, D_IN, D_IN, D_IN, NCOLS, 1.0f, 0, 0, 0);
  combine_ln<<<dim3(T_LEN, N_SEQ), 256, 0, stream>>>(
      G, k_b, v_b, ln_g, ln_b, skbf, qkbf, sv, qvbf);
  svtrans<<<dim3(18, 9, WAY), 256, 0, stream>>>(sv, svT);
  gemm_bt<1, 96><<<dim3(44, 3, WAY), 256, 0, stream>>>(
      qkbf, skbf, S, nullptr, nullptr,
      MQT, KS_PAD, D_OUT, D_OUT, D_OUT, KS_PAD, scale,
      0, (long)KS_PAD * D_OUT, (long)MQT * KS_PAD);
  softmax_align<<<dim3(7000), 256, 0, stream>>>(S, smbf, out + N_Q * WAY);
  gemm_bt<2, 128><<<dim3(44, 9, WAY), 256, 0, stream>>>(
      smbf, svT, nullptr, qvbf, DP,
      MQT, D_OUT, KS_PAD, KS_PAD, KS_PAD, 0, 1.0f,
      (long)MQT * KS_PAD, (long)D_OUT * KS_PAD, (long)MQT * DPC);
  logits_k<<<dim3(N_Q * WAY), 256, 0, stream>>>(DP, out);
}

// Round 7
// 233.564 us; speedup vs baseline: 1.0172x; 1.0172x over previous
//
#include <hip/hip_runtime.h>
#include <hip/hip_bf16.h>
#include <math.h>

// ---------------- constants ----------------
#define SEQ_LEN 8
#define D_IN 2048
#define D_OUT 1152
#define WAY 5
#define SHOT 5
#define N_SUPPORT 25
#define N_Q 100
#define N_SEQ 125
#define N_ROWS 1000        // N_SEQ * SEQ_LEN
#define T_LEN 56
#define KS_LEN 280         // SHOT * T_LEN
#define KS_PAD 288         // padded (16- and 32-multiple)
#define NCOLS 6912         // 6 * D_OUT
#define MQT 5600           // N_Q * T_LEN
#define DPC 18             // 9 col-tiles x 2 waves, proto dist partials

typedef __attribute__((ext_vector_type(4))) float f32x4;
typedef __attribute__((ext_vector_type(8))) short bf16x8;

__constant__ int TUP[T_LEN][3] = {
  {0,1,2},{0,1,3},{0,1,4},{0,1,5},{0,1,6},{0,1,7},{0,2,3},{0,2,4},{0,2,5},{0,2,6},
  {0,2,7},{0,3,4},{0,3,5},{0,3,6},{0,3,7},{0,4,5},{0,4,6},{0,4,7},{0,5,6},{0,5,7},
  {0,6,7},{1,2,3},{1,2,4},{1,2,5},{1,2,6},{1,2,7},{1,3,4},{1,3,5},{1,3,6},{1,3,7},
  {1,4,5},{1,4,6},{1,4,7},{1,5,6},{1,5,7},{1,6,7},{2,3,4},{2,3,5},{2,3,6},{2,3,7},
  {2,4,5},{2,4,6},{2,4,7},{2,5,6},{2,5,7},{2,6,7},{3,4,5},{3,4,6},{3,4,7},{3,5,6},
  {3,5,7},{3,6,7},{4,5,6},{4,5,7},{4,6,7},{5,6,7}
};

__device__ __forceinline__ ushort f2bf(float f) {
  union { float f; unsigned u; } v; v.f = f;
  unsigned r = v.u + 0x7FFFu + ((v.u >> 16) & 1u);   // RNE
  return (ushort)(r >> 16);
}
__device__ __forceinline__ float bf2f(ushort u) {
  union { unsigned u; float f; } v; v.u = ((unsigned)u) << 16;
  return v.f;
}
__device__ __forceinline__ void gload16(const void* g, const void* l) {
  __builtin_amdgcn_global_load_lds(
      (const __attribute__((address_space(1))) unsigned int*)g,
      (__attribute__((address_space(3))) unsigned int*)l, 16, 0, 0);
}
template<int N> __device__ __forceinline__ void vmw() {
  asm volatile("s_waitcnt vmcnt(%0)" :: "n"(N) : "memory");
}

// ---------------- kernel 0: Xbf = (input + PE) as bf16 ----------------
__global__ __launch_bounds__(256) void pe_add(const float* __restrict__ sup,
                                              const float* __restrict__ que,
                                              ushort* __restrict__ X) {
  int idx = blockIdx.x * 256 + threadIdx.x;
  if (idx >= N_ROWS * D_IN) return;
  int d = idx & (D_IN - 1);
  int r = idx >> 11;
  int i = r & 7;
  int h2 = d & ~1;
  float freq = expf((float)h2 * (-9.210340371976184f / (float)D_IN)); // ln(10000)
  float ang = (float)i * freq;
  float pe = ((d & 1) ? cosf(ang) : sinf(ang)) * 0.1f;
  float src = (r < N_SUPPORT * SEQ_LEN) ? sup[idx] : que[idx - N_SUPPORT * SEQ_LEN * D_IN];
  X[idx] = f2bf(src + pe);
}

// ---------------- kernel 1: WT[b*1152+n][k] = W_b[k][n] (bf16) -----------
__global__ __launch_bounds__(256) void wtrans(const float* __restrict__ kw,
                                              const float* __restrict__ vw,
                                              ushort* __restrict__ WT) {
  __shared__ float tile[64][65];
  int bx = blockIdx.x;              // 108 n-tiles (6 b-blocks x 18)
  int by = blockIdx.y;              // 32 k-tiles
  int b = bx / 18;
  int n0 = (bx % 18) * 64;
  int k0 = by * 64;
  const float* src = ((b & 1) ? vw : kw) + (size_t)(b >> 1) * D_IN * D_OUT;
  int tid = threadIdx.x;
#pragma unroll
  for (int it = 0; it < 4; ++it) {
    int lin4 = it * 256 + tid;            // 1024 float4 total
    int kk = lin4 >> 4;
    int n4 = (lin4 & 15) * 4;
    float4 v = *(const float4*)(src + (size_t)(k0 + kk) * D_OUT + n0 + n4);
    tile[kk][n4 + 0] = v.x; tile[kk][n4 + 1] = v.y;
    tile[kk][n4 + 2] = v.z; tile[kk][n4 + 3] = v.w;
  }
  __syncthreads();
#pragma unroll
  for (int it = 0; it < 4; ++it) {
    int lin = it * 1024 + tid * 4;        // 4096 elems, 4 k per thread
    int nn = lin >> 6, kk = lin & 63;
    ushort4 o;
    o.x = f2bf(tile[kk + 0][nn]); o.y = f2bf(tile[kk + 1][nn]);
    o.z = f2bf(tile[kk + 2][nn]); o.w = f2bf(tile[kk + 3][nn]);
    *(ushort4*)&WT[((size_t)(b * D_OUT + n0 + nn)) * D_IN + k0 + kk] = o;
  }
}

// ------- bt-form MFMA GEMM: dbuf LDS + counted vmcnt + XOR swizzle -------
// 128 x NT tile, BK=32, 4 waves 2x2 (wave covers 64 x NT/2).
// EPI 0: C=A*BT^T. EPI 1: C*alpha. EPI 2: proto + (qv-proto)^2 partials.
template<int EPI, int NT>
__global__ __launch_bounds__(256) void gemm_bt(
    const ushort* __restrict__ A, const ushort* __restrict__ BT,
    float* __restrict__ C,
    const ushort* __restrict__ QV, float* __restrict__ DP,
    int M, int N, int K, int lda, int ldb, int ldc, float alpha,
    long batchA, long batchB, long batchC) {
  constexpr int JF = NT / 32;          // col frags per wave
  constexpr int NCH = 8 + NT / 16;     // 16-row staging chunks (A + B)
  __shared__ ushort As[2][128][32];
  __shared__ ushort Bs[2][NT][32];
  int z = blockIdx.z;
  A  += (size_t)z * batchA;
  BT += (size_t)z * batchB;
  if constexpr (EPI < 2) C  += (size_t)z * batchC;
  else                   DP += (size_t)z * batchC;

  int tid = threadIdx.x;
  int wid = tid >> 6, lane = tid & 63;
  int l16 = lane & 15, lk = lane >> 4;
  int wr = wid >> 1, wc = wid & 1;
  int row0 = blockIdx.x * 128, col0 = blockIdx.y * NT;
  int lrow = lane >> 2;
  // source k-slot pre-swizzle: LDS[row][s] holds global slot s ^ ((row>>1)&3)
  int lcol = ((lane & 3) ^ ((lane >> 3) & 3)) * 8;
  // ds_read: logical slot lk lives at LDS slot lk ^ ((l16>>1)&3)
  int rslot = (lk ^ ((l16 >> 1) & 3)) * 8;

  auto stage = [&](int buf, int t) {
    int k0 = t * 32;
    for (int c = wid; c < NCH; c += 4) {            // wave-uniform chunks
      if (c < 8) {
        int grow = row0 + c * 16 + lrow;
        grow = grow < M ? grow : M - 1;
        gload16(A + (size_t)grow * lda + k0 + lcol, &As[buf][c * 16][0]);
      } else {
        int gcol = col0 + (c - 8) * 16 + lrow;
        gcol = gcol < N ? gcol : N - 1;
        gload16(BT + (size_t)gcol * ldb + k0 + lcol, &Bs[buf][(c - 8) * 16][0]);
      }
    }
  };

  f32x4 acc[4][JF] = {};
  int nk = K / 32;
  stage(0, 0);
  for (int t = 0; t < nk; ++t) {
    int cur = t & 1;
    if (t + 1 < nk) {
      stage(cur ^ 1, t + 1);
      if constexpr ((NCH & 3) == 0) {
        vmw<NCH / 4>();
      } else {
        if (wid < (NCH & 3)) vmw<NCH / 4 + 1>(); else vmw<NCH / 4>();
      }
    } else {
      vmw<0>();
    }
    __builtin_amdgcn_s_barrier();
    __builtin_amdgcn_sched_barrier(0);
    bf16x8 af[4], bv[JF];
#pragma unroll
    for (int m = 0; m < 4; ++m)
      af[m] = *(const bf16x8*)&As[cur][wr * 64 + m * 16 + l16][rslot];
#pragma unroll
    for (int j = 0; j < JF; ++j)
      bv[j] = *(const bf16x8*)&Bs[cur][wc * (NT / 2) + j * 16 + l16][rslot];
#pragma unroll
    for (int m = 0; m < 4; ++m)
#pragma unroll
      for (int j = 0; j < JF; ++j)
        acc[m][j] = __builtin_amdgcn_mfma_f32_16x16x32_bf16(af[m], bv[j], acc[m][j], 0, 0, 0);
    __builtin_amdgcn_sched_barrier(0);
    __builtin_amdgcn_s_barrier();
  }

  if constexpr (EPI < 2) {
#pragma unroll
    for (int m = 0; m < 4; ++m)
#pragma unroll
      for (int j = 0; j < JF; ++j) {
        int col = col0 + wc * (NT / 2) + j * 16 + l16;
#pragma unroll
        for (int r = 0; r < 4; ++r) {
          int row = row0 + wr * 64 + m * 16 + lk * 4 + r;
          if (row < M && col < N)
            C[(size_t)row * ldc + col] = (EPI == 1) ? acc[m][j][r] * alpha : acc[m][j][r];
        }
      }
  } else {
    float sq[4][4] = {};
#pragma unroll
    for (int m = 0; m < 4; ++m)
#pragma unroll
      for (int j = 0; j < JF; ++j) {
        int col = col0 + wc * (NT / 2) + j * 16 + l16;   // N=1152 exact
#pragma unroll
        for (int r = 0; r < 4; ++r) {
          int row = row0 + wr * 64 + m * 16 + lk * 4 + r;
          if (row < M) {
            float qvv = bf2f(QV[(size_t)row * D_OUT + col]);
            float d = qvv - acc[m][j][r];
            sq[m][r] += d * d;
          }
        }
      }
#pragma unroll
    for (int m = 0; m < 4; ++m)
#pragma unroll
      for (int r = 0; r < 4; ++r) {
        sq[m][r] += __shfl_xor(sq[m][r], 1);
        sq[m][r] += __shfl_xor(sq[m][r], 2);
        sq[m][r] += __shfl_xor(sq[m][r], 4);
        sq[m][r] += __shfl_xor(sq[m][r], 8);
      }
    if (l16 == 0) {
#pragma unroll
      for (int m = 0; m < 4; ++m)
#pragma unroll
        for (int r = 0; r < 4; ++r) {
          int row = row0 + wr * 64 + m * 16 + lk * 4 + r;
          if (row < M) DP[(size_t)row * DPC + blockIdx.y * 2 + wc] = sq[m][r];
        }
    }
  }
}

// ---------------- kernel 2: tuple-combine + bias + LayerNorm(K) -----------
__global__ __launch_bounds__(256) void combine_ln(const float* __restrict__ G,
                                                  const float* __restrict__ kb,
                                                  const float* __restrict__ vb,
                                                  const float* __restrict__ lng,
                                                  const float* __restrict__ lnb,
                                                  ushort* __restrict__ skbf,
                                                  ushort* __restrict__ qkbf,
                                                  ushort* __restrict__ sv,
                                                  ushort* __restrict__ qvbf) {
  int t = blockIdx.x;   // 0..55
  int n = blockIdx.y;   // 0..124
  const float* g0 = G + (size_t)(n * 8 + TUP[t][0]) * NCOLS;
  const float* g1 = G + (size_t)(n * 8 + TUP[t][1]) * NCOLS + 2 * D_OUT;
  const float* g2 = G + (size_t)(n * 8 + TUP[t][2]) * NCOLS + 4 * D_OUT;
  __shared__ float kbuf[D_OUT];
  __shared__ float red1[256], red2[256];
  int tid = threadIdx.x;
  bool isq = (n >= N_SUPPORT);
  int c = n / SHOT, s = n % SHOT;
  ushort* vout = isq ? qvbf + ((size_t)(n - N_SUPPORT) * T_LEN + t) * D_OUT
                     : sv + ((size_t)c * KS_PAD + s * T_LEN + t) * D_OUT;
  float s1 = 0.f, s2 = 0.f;
  for (int d4 = tid; d4 < D_OUT / 4; d4 += 256) {
    int d = d4 * 4;
    float4 a = *(const float4*)(g0 + d);
    float4 b = *(const float4*)(g0 + D_OUT + d);
    float4 c1 = *(const float4*)(g1 + d);
    float4 c2 = *(const float4*)(g1 + D_OUT + d);
    float4 e1 = *(const float4*)(g2 + d);
    float4 e2 = *(const float4*)(g2 + D_OUT + d);
    float4 kb4 = *(const float4*)(kb + d);
    float4 vb4 = *(const float4*)(vb + d);
    float kx = a.x + c1.x + e1.x + kb4.x, ky = a.y + c1.y + e1.y + kb4.y;
    float kz = a.z + c1.z + e1.z + kb4.z, kw = a.w + c1.w + e1.w + kb4.w;
    float vx = b.x + c2.x + e2.x + vb4.x, vy = b.y + c2.y + e2.y + vb4.y;
    float vz = b.z + c2.z + e2.z + vb4.z, vw = b.w + c2.w + e2.w + vb4.w;
    *(float4*)(kbuf + d) = make_float4(kx, ky, kz, kw);
    ushort4 vv; vv.x = f2bf(vx); vv.y = f2bf(vy); vv.z = f2bf(vz); vv.w = f2bf(vw);
    *(ushort4*)(vout + d) = vv;
    s1 += kx + ky + kz + kw;
    s2 += kx * kx + ky * ky + kz * kz + kw * kw;
  }
  red1[tid] = s1; red2[tid] = s2;
  __syncthreads();
  for (int sft = 128; sft > 0; sft >>= 1) {
    if (tid < sft) { red1[tid] += red1[tid + sft]; red2[tid] += red2[tid + sft]; }
    __syncthreads();
  }
  float mu = red1[0] * (1.0f / D_OUT);
  float var = red2[0] * (1.0f / D_OUT) - mu * mu;
  float rs = rsqrtf(var + 1e-5f);
  ushort* kout = isq ? qkbf + ((size_t)(n - N_SUPPORT) * T_LEN + t) * D_OUT
                     : skbf + ((size_t)c * KS_PAD + s * T_LEN + t) * D_OUT;
  for (int d4 = tid; d4 < D_OUT / 4; d4 += 256) {
    int d = d4 * 4;
    float4 kv = *(const float4*)(kbuf + d);
    float4 g4 = *(const float4*)(lng + d);
    float4 b4 = *(const float4*)(lnb + d);
    ushort4 o;
    o.x = f2bf((kv.x - mu) * rs * g4.x + b4.x);
    o.y = f2bf((kv.y - mu) * rs * g4.y + b4.y);
    o.z = f2bf((kv.z - mu) * rs * g4.z + b4.z);
    o.w = f2bf((kv.w - mu) * rs * g4.w + b4.w);
    *(ushort4*)(kout + d) = o;
  }
}

// ---------------- kernel 2b: svT[c][d][ks] = sv[c][ks][d], zero pad -------
__global__ __launch_bounds__(256) void svtrans(const ushort* __restrict__ sv,
                                               ushort* __restrict__ svT) {
  __shared__ ushort tile[32][65];
  int c = blockIdx.z;
  int d0 = blockIdx.x * 64;   // 18 tiles
  int k0 = blockIdx.y * 32;   // 9 tiles
  const ushort* src = sv + (size_t)c * KS_PAD * D_OUT;
  ushort* dst = svT + (size_t)c * D_OUT * KS_PAD;
  int tid = threadIdx.x;
#pragma unroll
  for (int it = 0; it < 8; ++it) {
    int lin = it * 256 + tid;
    int ks = k0 + (lin >> 6), d = d0 + (lin & 63);
    tile[lin >> 6][lin & 63] = (ks < KS_LEN) ? src[(size_t)ks * D_OUT + d] : (ushort)0;
  }
  __syncthreads();
#pragma unroll
  for (int it = 0; it < 8; ++it) {
    int lin = it * 256 + tid;
    int d = lin >> 5, ks = lin & 31;
    dst[(size_t)(d0 + d) * KS_PAD + k0 + ks] = tile[ks][d];
  }
}

// ---------------- kernel 3: softmax (fp32) + align + sm bf16 -------------
__global__ __launch_bounds__(256) void softmax_align(const float* __restrict__ S,
                                                     ushort* __restrict__ sm,
                                                     float* __restrict__ align_out) {
  __shared__ float pl[4][KS_LEN];
  int wid = threadIdx.x >> 6, lane = threadIdx.x & 63;
  int row = blockIdx.x * 4 + wid;         // 0..27999
  const float* src = S + (size_t)row * KS_PAD;
  float v[5];
  float mx = -1e30f;
#pragma unroll
  for (int j = 0; j < 5; ++j) {
    int ks = lane + j * 64;
    v[j] = (ks < KS_LEN) ? src[ks] : -1e30f;
    mx = fmaxf(mx, v[j]);
  }
#pragma unroll
  for (int m = 32; m > 0; m >>= 1) mx = fmaxf(mx, __shfl_xor(mx, m));
  float sum = 0.f;
  float p[5];
#pragma unroll
  for (int j = 0; j < 5; ++j) {
    int ks = lane + j * 64;
    p[j] = (ks < KS_LEN) ? expf(v[j] - mx) : 0.f;
    sum += p[j];
  }
#pragma unroll
  for (int m = 32; m > 0; m >>= 1) sum += __shfl_xor(sum, m);
  float inv = 1.0f / sum;
  ushort* dst = sm + (size_t)row * KS_PAD;
#pragma unroll
  for (int j = 0; j < 5; ++j) {
    int ks = lane + j * 64;
    if (ks < KS_PAD) dst[ks] = f2bf((ks < KS_LEN) ? p[j] * inv : 0.f);
  }
  int c = row / MQT;
  if (c == WAY - 1) {
#pragma unroll
    for (int j = 0; j < 5; ++j) {
      int ks = lane + j * 64;
      if (ks < KS_LEN) pl[wid][ks] = p[j] * inv;
    }
    __syncthreads();
    if (lane < T_LEN) {
      float a = 0.f;
#pragma unroll
      for (int k = 0; k < SHOT; ++k) a += pl[wid][k * T_LEN + lane];
      int qt = row - (WAY - 1) * MQT;
      align_out[(size_t)(qt / T_LEN) * (T_LEN * T_LEN) + (qt % T_LEN) * T_LEN + lane] = a;
    }
  }
}

// ---------------- kernel 4: logits -----------------------------------
__global__ __launch_bounds__(256) void logits_k(const float* __restrict__ DP,
                                                float* __restrict__ out) {
  __shared__ float red[256];
  int q = blockIdx.x / WAY, c = blockIdx.x % WAY;
  const float* base = DP + ((size_t)c * MQT + q * T_LEN) * DPC;  // 56*18=1008
  int tid = threadIdx.x;
  float s = 0.f;
  for (int i = tid; i < T_LEN * DPC; i += 256) s += base[i];
  red[tid] = s;
  __syncthreads();
  for (int sft = 128; sft > 0; sft >>= 1) {
    if (tid < sft) red[tid] += red[tid + sft];
    __syncthreads();
  }
  if (tid == 0) out[blockIdx.x] = -red[0] * (1.0f / T_LEN);
}

// ---------------- launch ----------------
extern "C" void kernel_launch(void* const* d_in, const int* in_sizes, int n_in,
                              void* d_out, int out_size, void* d_ws, size_t ws_size,
                              hipStream_t stream) {
  const float* sup  = (const float*)d_in[0];
  const float* que  = (const float*)d_in[1];
  const float* k_w  = (const float*)d_in[3];
  const float* k_b  = (const float*)d_in[4];
  const float* v_w  = (const float*)d_in[5];
  const float* v_b  = (const float*)d_in[6];
  const float* ln_g = (const float*)d_in[7];
  const float* ln_b = (const float*)d_in[8];
  float* out = (float*)d_out;

  char* w = (char*)d_ws;
  // Live ranges allow heavy aliasing; footprint kept at 92.5 MB.
  ushort* Xbf  = (ushort*)(w + 0);            //  4,096,000  (dead after proj)
  ushort* WT   = (ushort*)(w + 4096000);      // 28,311,552  (dead after proj)
  float*  G    = (float*)(w + 32407552);      // 27,648,000  (dead after combine)
  ushort* sv   = (ushort*)(w + 0);            //  3,317,760  (alias Xbf; dead after svtrans)
  float*  S    = (float*)(w + 0);             // 32,256,000  (alias; dead after softmax)
  ushort* smbf = (ushort*)(w + 32407552);     // 16,128,000  (alias G)
  float*  DP   = (float*)(w + 0);             //  2,016,000  (alias S after softmax)
  ushort* qkbf = (ushort*)(w + 60055552);     // 12,902,400
  ushort* skbf = (ushort*)(w + 72957952);     //  3,317,760
  ushort* svT  = (ushort*)(w + 76275712);     //  3,317,760
  ushort* qvbf = (ushort*)(w + 79593472);     // 12,902,400 -> end 92,495,872

  const float scale = 0.02946278254943948f; // 1/sqrt(1152)

  pe_add<<<dim3(8000), 256, 0, stream>>>(sup, que, Xbf);
  wtrans<<<dim3(108, 32), 256, 0, stream>>>(k_w, v_w, WT);
  gemm_bt<0, 64><<<dim3(8, 108, 1), 256, 0, stream>>>(
      Xbf, WT, G, nullptr, nullptr,
      N_ROWS, NCOLS, D_IN, D_IN, D_IN, NCOLS, 1.0f, 0, 0, 0);
  combine_ln<<<dim3(T_LEN, N_SEQ), 256, 0, stream>>>(
      G, k_b, v_b, ln_g, ln_b, skbf, qkbf, sv, qvbf);
  svtrans<<<dim3(18, 9, WAY), 256, 0, stream>>>(sv, svT);
  gemm_bt<1, 96><<<dim3(44, 3, WAY), 256, 0, stream>>>(
      qkbf, skbf, S, nullptr, nullptr,
      MQT, KS_PAD, D_OUT, D_OUT, D_OUT, KS_PAD, scale,
      0, (long)KS_PAD * D_OUT, (long)MQT * KS_PAD);
  softmax_align<<<dim3(7000), 256, 0, stream>>>(S, smbf, out + N_Q * WAY);
  gemm_bt<2, 128><<<dim3(44, 9, WAY), 256, 0, stream>>>(
      smbf, svT, nullptr, qvbf, DP,
      MQT, D_OUT, KS_PAD, KS_PAD, KS_PAD, 0, 1.0f,
      (long)MQT * KS_PAD, (long)D_OUT * KS_PAD, (long)MQT * DPC);
  logits_k<<<dim3(N_Q * WAY), 256, 0, stream>>>(DP, out);
}

// Round 9
// 195.943 us; speedup vs baseline: 1.2125x; 1.1920x over previous
//
#include <hip/hip_runtime.h>
#include <hip/hip_bf16.h>
#include <math.h>

// ---------------- constants ----------------
#define SEQ_LEN 8
#define D_IN 2048
#define D_OUT 1152
#define WAY 5
#define SHOT 5
#define N_SUPPORT 25
#define N_Q 100
#define N_SEQ 125
#define N_ROWS 1000        // N_SEQ * SEQ_LEN
#define T_LEN 56
#define KS_LEN 280         // SHOT * T_LEN
#define KS_PAD 288         // padded (16- and 32-multiple)
#define NCOLS 6912         // 6 * D_OUT
#define MQT 5600           // N_Q * T_LEN
#define DPC 9              // 9 col-tiles, proto dist partials

typedef __attribute__((ext_vector_type(4))) float f32x4;
typedef __attribute__((ext_vector_type(8))) short bf16x8;

__constant__ int TUP[T_LEN][3] = {
  {0,1,2},{0,1,3},{0,1,4},{0,1,5},{0,1,6},{0,1,7},{0,2,3},{0,2,4},{0,2,5},{0,2,6},
  {0,2,7},{0,3,4},{0,3,5},{0,3,6},{0,3,7},{0,4,5},{0,4,6},{0,4,7},{0,5,6},{0,5,7},
  {0,6,7},{1,2,3},{1,2,4},{1,2,5},{1,2,6},{1,2,7},{1,3,4},{1,3,5},{1,3,6},{1,3,7},
  {1,4,5},{1,4,6},{1,4,7},{1,5,6},{1,5,7},{1,6,7},{2,3,4},{2,3,5},{2,3,6},{2,3,7},
  {2,4,5},{2,4,6},{2,4,7},{2,5,6},{2,5,7},{2,6,7},{3,4,5},{3,4,6},{3,4,7},{3,5,6},
  {3,5,7},{3,6,7},{4,5,6},{4,5,7},{4,6,7},{5,6,7}
};

__device__ __forceinline__ ushort f2bf(float f) {
  union { float f; unsigned u; } v; v.f = f;
  unsigned r = v.u + 0x7FFFu + ((v.u >> 16) & 1u);   // RNE
  return (ushort)(r >> 16);
}
__device__ __forceinline__ float bf2f(ushort u) {
  union { unsigned u; float f; } v; v.u = ((unsigned)u) << 16;
  return v.f;
}
__device__ __forceinline__ void gload16(const void* g, const void* l) {
  __builtin_amdgcn_global_load_lds(
      (const __attribute__((address_space(1))) unsigned int*)g,
      (__attribute__((address_space(3))) unsigned int*)l, 16, 0, 0);
}
template<int N> __device__ __forceinline__ void vmw() {
  asm volatile("s_waitcnt vmcnt(%0)" :: "n"(N) : "memory");
}

// ---------------- kernel 0: Xbf = (input + PE) as bf16 ----------------
__global__ __launch_bounds__(256) void pe_add(const float* __restrict__ sup,
                                              const float* __restrict__ que,
                                              ushort* __restrict__ X) {
  int idx = blockIdx.x * 256 + threadIdx.x;
  if (idx >= N_ROWS * D_IN) return;
  int d = idx & (D_IN - 1);
  int r = idx >> 11;
  int i = r & 7;
  int h2 = d & ~1;
  float freq = expf((float)h2 * (-9.210340371976184f / (float)D_IN)); // ln(10000)
  float ang = (float)i * freq;
  float pe = ((d & 1) ? cosf(ang) : sinf(ang)) * 0.1f;
  float src = (r < N_SUPPORT * SEQ_LEN) ? sup[idx] : que[idx - N_SUPPORT * SEQ_LEN * D_IN];
  X[idx] = f2bf(src + pe);
}

// ---------------- kernel 1: WT[b*1152+n][k] = W_b[k][n] (bf16) -----------
__global__ __launch_bounds__(256) void wtrans(const float* __restrict__ kw,
                                              const float* __restrict__ vw,
                                              ushort* __restrict__ WT) {
  __shared__ float tile[64][65];
  int bx = blockIdx.x;              // 108 n-tiles (6 b-blocks x 18)
  int by = blockIdx.y;              // 32 k-tiles
  int b = bx / 18;
  int n0 = (bx % 18) * 64;
  int k0 = by * 64;
  const float* src = ((b & 1) ? vw : kw) + (size_t)(b >> 1) * D_IN * D_OUT;
  int tid = threadIdx.x;
#pragma unroll
  for (int it = 0; it < 4; ++it) {
    int lin4 = it * 256 + tid;            // 1024 float4 total
    int kk = lin4 >> 4;
    int n4 = (lin4 & 15) * 4;
    float4 v = *(const float4*)(src + (size_t)(k0 + kk) * D_OUT + n0 + n4);
    tile[kk][n4 + 0] = v.x; tile[kk][n4 + 1] = v.y;
    tile[kk][n4 + 2] = v.z; tile[kk][n4 + 3] = v.w;
  }
  __syncthreads();
#pragma unroll
  for (int it = 0; it < 4; ++it) {
    int lin = it * 1024 + tid * 4;        // 4096 elems, 4 k per thread
    int nn = lin >> 6, kk = lin & 63;
    ushort4 o;
    o.x = f2bf(tile[kk + 0][nn]); o.y = f2bf(tile[kk + 1][nn]);
    o.z = f2bf(tile[kk + 2][nn]); o.w = f2bf(tile[kk + 3][nn]);
    *(ushort4*)&WT[((size_t)(b * D_OUT + n0 + nn)) * D_IN + k0 + kk] = o;
  }
}

// ------- bt-form MFMA GEMM: dbuf LDS + counted vmcnt + XOR swizzle -------
// (used for proj and scores; proto has its own panel-resident kernel)
template<int EPI, int NT>
__global__ __launch_bounds__(256) void gemm_bt(
    const ushort* __restrict__ A, const ushort* __restrict__ BT,
    float* __restrict__ C,
    int M, int N, int K, int lda, int ldb, int ldc, float alpha,
    long batchA, long batchB, long batchC) {
  constexpr int JF = NT / 32;          // col frags per wave
  constexpr int NCH = 8 + NT / 16;     // 16-row staging chunks (A + B)
  __shared__ ushort As[2][128][32];
  __shared__ ushort Bs[2][NT][32];
  int z = blockIdx.z;
  A  += (size_t)z * batchA;
  BT += (size_t)z * batchB;
  C  += (size_t)z * batchC;

  int tid = threadIdx.x;
  int wid = tid >> 6, lane = tid & 63;
  int l16 = lane & 15, lk = lane >> 4;
  int wr = wid >> 1, wc = wid & 1;
  int row0 = blockIdx.x * 128, col0 = blockIdx.y * NT;
  int lrow = lane >> 2;
  // source k-slot pre-swizzle: LDS[row][s] holds global slot s ^ ((row>>1)&3)
  int lcol = ((lane & 3) ^ ((lane >> 3) & 3)) * 8;
  // ds_read: logical slot lk lives at LDS slot lk ^ ((l16>>1)&3)
  int rslot = (lk ^ ((l16 >> 1) & 3)) * 8;

  auto stage = [&](int buf, int t) {
    int k0 = t * 32;
    for (int c = wid; c < NCH; c += 4) {            // wave-uniform chunks
      if (c < 8) {
        int grow = row0 + c * 16 + lrow;
        grow = grow < M ? grow : M - 1;
        gload16(A + (size_t)grow * lda + k0 + lcol, &As[buf][c * 16][0]);
      } else {
        int gcol = col0 + (c - 8) * 16 + lrow;
        gcol = gcol < N ? gcol : N - 1;
        gload16(BT + (size_t)gcol * ldb + k0 + lcol, &Bs[buf][(c - 8) * 16][0]);
      }
    }
  };

  f32x4 acc[4][JF] = {};
  int nk = K / 32;
  stage(0, 0);
  for (int t = 0; t < nk; ++t) {
    int cur = t & 1;
    if (t + 1 < nk) {
      stage(cur ^ 1, t + 1);
      if constexpr ((NCH & 3) == 0) {
        vmw<NCH / 4>();
      } else {
        if (wid < (NCH & 3)) vmw<NCH / 4 + 1>(); else vmw<NCH / 4>();
      }
    } else {
      vmw<0>();
    }
    __builtin_amdgcn_s_barrier();
    __builtin_amdgcn_sched_barrier(0);
    bf16x8 af[4], bv[JF];
#pragma unroll
    for (int m = 0; m < 4; ++m)
      af[m] = *(const bf16x8*)&As[cur][wr * 64 + m * 16 + l16][rslot];
#pragma unroll
    for (int j = 0; j < JF; ++j)
      bv[j] = *(const bf16x8*)&Bs[cur][wc * (NT / 2) + j * 16 + l16][rslot];
#pragma unroll
    for (int m = 0; m < 4; ++m)
#pragma unroll
      for (int j = 0; j < JF; ++j)
        acc[m][j] = __builtin_amdgcn_mfma_f32_16x16x32_bf16(af[m], bv[j], acc[m][j], 0, 0, 0);
    __builtin_amdgcn_sched_barrier(0);
    __builtin_amdgcn_s_barrier();
  }

#pragma unroll
  for (int m = 0; m < 4; ++m)
#pragma unroll
    for (int j = 0; j < JF; ++j) {
      int col = col0 + wc * (NT / 2) + j * 16 + l16;
#pragma unroll
      for (int r = 0; r < 4; ++r) {
        int row = row0 + wr * 64 + m * 16 + lk * 4 + r;
        if (row < M && col < N)
          C[(size_t)row * ldc + col] = (EPI == 1) ? acc[m][j][r] * alpha : acc[m][j][r];
      }
    }
}

// ------- proto: B-panel-resident, barrier-free K-loop, fused dist --------
// block: 128 rows x 128 cols x class. B panel (128x288 bf16) lives in LDS.
// wave w owns rows [row0+32w, +32); A streamed from global (L2/L3).
__global__ __launch_bounds__(256) void pv_dist(const ushort* __restrict__ SM,
                                               const ushort* __restrict__ SVT,
                                               const ushort* __restrict__ QV,
                                               float* __restrict__ DP) {
  __shared__ ushort Bs[128][296];   // +8 pad: ds_read_b128 conflict-light
  int tid = threadIdx.x, wid = tid >> 6, lane = tid & 63;
  int l16 = lane & 15, lk = lane >> 4;
  int row0 = blockIdx.x * 128, col0 = blockIdx.y * 128, c = blockIdx.z;
  const ushort* sm = SM + (size_t)c * MQT * KS_PAD;
  const ushort* bt = SVT + ((size_t)c * D_OUT + col0) * KS_PAD;
  // panel load: 2 threads per row, 18 x 16B each (full 288-ushort row)
  {
    int r = tid >> 1, h = tid & 1;
    const ushort* srcr = bt + (size_t)r * KS_PAD + h * 144;
#pragma unroll
    for (int i = 0; i < 18; ++i) {
      uint4 v = *(const uint4*)(srcr + i * 8);
      *(uint4*)&Bs[r][h * 144 + i * 8] = v;
    }
  }
  __syncthreads();

  int ra0 = row0 + wid * 32 + l16;      if (ra0 > MQT - 1) ra0 = MQT - 1;
  int ra1 = row0 + wid * 32 + 16 + l16; if (ra1 > MQT - 1) ra1 = MQT - 1;
  const ushort* a0 = sm + (size_t)ra0 * KS_PAD + lk * 8;
  const ushort* a1 = sm + (size_t)ra1 * KS_PAD + lk * 8;

  f32x4 acc[2][8] = {};
#pragma unroll
  for (int ks = 0; ks < 9; ++ks) {
    bf16x8 af0 = *(const bf16x8*)(a0 + ks * 32);
    bf16x8 af1 = *(const bf16x8*)(a1 + ks * 32);
    bf16x8 bv[8];
#pragma unroll
    for (int j = 0; j < 8; ++j)
      bv[j] = *(const bf16x8*)&Bs[j * 16 + l16][ks * 32 + lk * 8];
#pragma unroll
    for (int j = 0; j < 8; ++j) {
      acc[0][j] = __builtin_amdgcn_mfma_f32_16x16x32_bf16(af0, bv[j], acc[0][j], 0, 0, 0);
      acc[1][j] = __builtin_amdgcn_mfma_f32_16x16x32_bf16(af1, bv[j], acc[1][j], 0, 0, 0);
    }
  }

  // fused (qv - proto)^2 partials
  float sq[2][4] = {};
#pragma unroll
  for (int m = 0; m < 2; ++m)
#pragma unroll
    for (int r = 0; r < 4; ++r) {
      int row = row0 + wid * 32 + m * 16 + lk * 4 + r;
      int rowc = row < MQT ? row : MQT - 1;
      const ushort* qvr = QV + (size_t)rowc * D_OUT + col0;
#pragma unroll
      for (int j = 0; j < 8; ++j) {
        float qvv = bf2f(qvr[j * 16 + l16]);
        float d = qvv - acc[m][j][r];
        sq[m][r] += d * d;
      }
    }
#pragma unroll
  for (int m = 0; m < 2; ++m)
#pragma unroll
    for (int r = 0; r < 4; ++r) {
      sq[m][r] += __shfl_xor(sq[m][r], 1);
      sq[m][r] += __shfl_xor(sq[m][r], 2);
      sq[m][r] += __shfl_xor(sq[m][r], 4);
      sq[m][r] += __shfl_xor(sq[m][r], 8);
    }
  if (l16 == 0) {
    float* dp = DP + (size_t)c * MQT * DPC;
#pragma unroll
    for (int m = 0; m < 2; ++m)
#pragma unroll
      for (int r = 0; r < 4; ++r) {
        int row = row0 + wid * 32 + m * 16 + lk * 4 + r;
        if (row < MQT) dp[(size_t)row * DPC + blockIdx.y] = sq[m][r];
      }
  }
}

// ------- kernel 2: tuple-combine + bias + LN(K), wave-per-row ------------
__global__ __launch_bounds__(256) void combine_ln(const float* __restrict__ G,
                                                  const float* __restrict__ kb,
                                                  const float* __restrict__ vb,
                                                  const float* __restrict__ lng,
                                                  const float* __restrict__ lnb,
                                                  ushort* __restrict__ skbf,
                                                  ushort* __restrict__ qkbf,
                                                  ushort* __restrict__ sv,
                                                  ushort* __restrict__ qvbf) {
  int gw = blockIdx.x * 4 + (threadIdx.x >> 6);   // 0..6999
  int lane = threadIdx.x & 63;
  int t = gw % T_LEN, n = gw / T_LEN;
  const float* g0 = G + (size_t)(n * 8 + TUP[t][0]) * NCOLS;
  const float* g1 = G + (size_t)(n * 8 + TUP[t][1]) * NCOLS + 2 * D_OUT;
  const float* g2 = G + (size_t)(n * 8 + TUP[t][2]) * NCOLS + 4 * D_OUT;
  bool isq = (n >= N_SUPPORT);
  int c = n / SHOT, s = n % SHOT;
  ushort* vout = isq ? qvbf + ((size_t)(n - N_SUPPORT) * T_LEN + t) * D_OUT
                     : sv + ((size_t)c * KS_PAD + s * T_LEN + t) * D_OUT;
  ushort* kout = isq ? qkbf + ((size_t)(n - N_SUPPORT) * T_LEN + t) * D_OUT
                     : skbf + ((size_t)c * KS_PAD + s * T_LEN + t) * D_OUT;
  float kvx[9], kvy[9], s1 = 0.f, s2 = 0.f;
#pragma unroll
  for (int i = 0; i < 9; ++i) {
    int d = i * 128 + lane * 2;
    float2 a = *(const float2*)(g0 + d);
    float2 b = *(const float2*)(g0 + D_OUT + d);
    float2 c1 = *(const float2*)(g1 + d);
    float2 c2 = *(const float2*)(g1 + D_OUT + d);
    float2 e1 = *(const float2*)(g2 + d);
    float2 e2 = *(const float2*)(g2 + D_OUT + d);
    float2 kb2 = *(const float2*)(kb + d);
    float2 vb2 = *(const float2*)(vb + d);
    float kx = a.x + c1.x + e1.x + kb2.x;
    float ky = a.y + c1.y + e1.y + kb2.y;
    float vx = b.x + c2.x + e2.x + vb2.x;
    float vy = b.y + c2.y + e2.y + vb2.y;
    kvx[i] = kx; kvy[i] = ky;
    ushort2 vv; vv.x = f2bf(vx); vv.y = f2bf(vy);
    *(ushort2*)(vout + d) = vv;
    s1 += kx + ky;
    s2 += kx * kx + ky * ky;
  }
#pragma unroll
  for (int m = 32; m > 0; m >>= 1) {
    s1 += __shfl_xor(s1, m);
    s2 += __shfl_xor(s2, m);
  }
  float mu = s1 * (1.0f / D_OUT);
  float var = s2 * (1.0f / D_OUT) - mu * mu;
  float rs = rsqrtf(var + 1e-5f);
#pragma unroll
  for (int i = 0; i < 9; ++i) {
    int d = i * 128 + lane * 2;
    float2 g2v = *(const float2*)(lng + d);
    float2 b2v = *(const float2*)(lnb + d);
    ushort2 o;
    o.x = f2bf((kvx[i] - mu) * rs * g2v.x + b2v.x);
    o.y = f2bf((kvy[i] - mu) * rs * g2v.y + b2v.y);
    *(ushort2*)(kout + d) = o;
  }
}

// ---------------- kernel 2b: svT[c][d][ks] = sv[c][ks][d], zero pad -------
__global__ __launch_bounds__(256) void svtrans(const ushort* __restrict__ sv,
                                               ushort* __restrict__ svT) {
  __shared__ ushort tile[32][65];
  int c = blockIdx.z;
  int d0 = blockIdx.x * 64;   // 18 tiles
  int k0 = blockIdx.y * 32;   // 9 tiles
  const ushort* src = sv + (size_t)c * KS_PAD * D_OUT;
  ushort* dst = svT + (size_t)c * D_OUT * KS_PAD;
  int tid = threadIdx.x;
#pragma unroll
  for (int it = 0; it < 8; ++it) {
    int lin = it * 256 + tid;
    int ks = k0 + (lin >> 6), d = d0 + (lin & 63);
    tile[lin >> 6][lin & 63] = (ks < KS_LEN) ? src[(size_t)ks * D_OUT + d] : (ushort)0;
  }
  __syncthreads();
#pragma unroll
  for (int it = 0; it < 8; ++it) {
    int lin = it * 256 + tid;
    int d = lin >> 5, ks = lin & 31;
    dst[(size_t)(d0 + d) * KS_PAD + k0 + ks] = tile[ks][d];
  }
}

// ---------------- kernel 3: softmax (fp32) + align + sm bf16 -------------
__global__ __launch_bounds__(256) void softmax_align(const float* __restrict__ S,
                                                     ushort* __restrict__ sm,
                                                     float* __restrict__ align_out) {
  __shared__ float pl[4][KS_LEN];
  int wid = threadIdx.x >> 6, lane = threadIdx.x & 63;
  int row = blockIdx.x * 4 + wid;         // 0..27999
  const float* src = S + (size_t)row * KS_PAD;
  float v[5];
  float mx = -1e30f;
#pragma unroll
  for (int j = 0; j < 5; ++j) {
    int ks = lane + j * 64;
    v[j] = (ks < KS_LEN) ? src[ks] : -1e30f;
    mx = fmaxf(mx, v[j]);
  }
#pragma unroll
  for (int m = 32; m > 0; m >>= 1) mx = fmaxf(mx, __shfl_xor(mx, m));
  float sum = 0.f;
  float p[5];
#pragma unroll
  for (int j = 0; j < 5; ++j) {
    int ks = lane + j * 64;
    p[j] = (ks < KS_LEN) ? expf(v[j] - mx) : 0.f;
    sum += p[j];
  }
#pragma unroll
  for (int m = 32; m > 0; m >>= 1) sum += __shfl_xor(sum, m);
  float inv = 1.0f / sum;
  ushort* dst = sm + (size_t)row * KS_PAD;
#pragma unroll
  for (int j = 0; j < 5; ++j) {
    int ks = lane + j * 64;
    if (ks < KS_PAD) dst[ks] = f2bf((ks < KS_LEN) ? p[j] * inv : 0.f);
  }
  int c = row / MQT;
  if (c == WAY - 1) {
#pragma unroll
    for (int j = 0; j < 5; ++j) {
      int ks = lane + j * 64;
      if (ks < KS_LEN) pl[wid][ks] = p[j] * inv;
    }
    __syncthreads();
    if (lane < T_LEN) {
      float a = 0.f;
#pragma unroll
      for (int k = 0; k < SHOT; ++k) a += pl[wid][k * T_LEN + lane];
      int qt = row - (WAY - 1) * MQT;
      align_out[(size_t)(qt / T_LEN) * (T_LEN * T_LEN) + (qt % T_LEN) * T_LEN + lane] = a;
    }
  }
}

// ---------------- kernel 4: logits -----------------------------------
__global__ __launch_bounds__(256) void logits_k(const float* __restrict__ DP,
                                                float* __restrict__ out) {
  __shared__ float red[256];
  int q = blockIdx.x / WAY, c = blockIdx.x % WAY;
  const float* base = DP + ((size_t)c * MQT + q * T_LEN) * DPC;  // 56*9=504
  int tid = threadIdx.x;
  float s = 0.f;
  for (int i = tid; i < T_LEN * DPC; i += 256) s += base[i];
  red[tid] = s;
  __syncthreads();
  for (int sft = 128; sft > 0; sft >>= 1) {
    if (tid < sft) red[tid] += red[tid + sft];
    __syncthreads();
  }
  if (tid == 0) out[blockIdx.x] = -red[0] * (1.0f / T_LEN);
}

// ---------------- launch ----------------
extern "C" void kernel_launch(void* const* d_in, const int* in_sizes, int n_in,
                              void* d_out, int out_size, void* d_ws, size_t ws_size,
                              hipStream_t stream) {
  const float* sup  = (const float*)d_in[0];
  const float* que  = (const float*)d_in[1];
  const float* k_w  = (const float*)d_in[3];
  const float* k_b  = (const float*)d_in[4];
  const float* v_w  = (const float*)d_in[5];
  const float* v_b  = (const float*)d_in[6];
  const float* ln_g = (const float*)d_in[7];
  const float* ln_b = (const float*)d_in[8];
  float* out = (float*)d_out;

  char* w = (char*)d_ws;
  // Live ranges allow heavy aliasing; footprint kept at 92.5 MB.
  ushort* Xbf  = (ushort*)(w + 0);            //  4,096,000  (dead after proj)
  ushort* WT   = (ushort*)(w + 4096000);      // 28,311,552  (dead after proj)
  float*  G    = (float*)(w + 32407552);      // 27,648,000  (dead after combine)
  ushort* sv   = (ushort*)(w + 0);            //  3,317,760  (alias Xbf; dead after svtrans)
  float*  S    = (float*)(w + 0);             // 32,256,000  (alias; dead after softmax)
  ushort* smbf = (ushort*)(w + 32407552);     // 16,128,000  (alias G)
  float*  DP   = (float*)(w + 0);             //  1,008,000  (alias S after softmax)
  ushort* qkbf = (ushort*)(w + 60055552);     // 12,902,400
  ushort* skbf = (ushort*)(w + 72957952);     //  3,317,760
  ushort* svT  = (ushort*)(w + 76275712);     //  3,317,760
  ushort* qvbf = (ushort*)(w + 79593472);     // 12,902,400 -> end 92,495,872

  const float scale = 0.02946278254943948f; // 1/sqrt(1152)

  pe_add<<<dim3(8000), 256, 0, stream>>>(sup, que, Xbf);
  wtrans<<<dim3(108, 32), 256, 0, stream>>>(k_w, v_w, WT);
  gemm_bt<0, 64><<<dim3(8, 108, 1), 256, 0, stream>>>(
      Xbf, WT, G,
      N_ROWS, NCOLS, D_IN, D_IN, D_IN, NCOLS, 1.0f, 0, 0, 0);
  combine_ln<<<dim3(1750), 256, 0, stream>>>(
      G, k_b, v_b, ln_g, ln_b, skbf, qkbf, sv, qvbf);
  svtrans<<<dim3(18, 9, WAY), 256, 0, stream>>>(sv, svT);
  gemm_bt<1, 96><<<dim3(44, 3, WAY), 256, 0, stream>>>(
      qkbf, skbf, S,
      MQT, KS_PAD, D_OUT, D_OUT, D_OUT, KS_PAD, scale,
      0, (long)KS_PAD * D_OUT, (long)MQT * KS_PAD);
  softmax_align<<<dim3(7000), 256, 0, stream>>>(S, smbf, out + N_Q * WAY);
  pv_dist<<<dim3(44, 9, WAY), 256, 0, stream>>>(smbf, svT, qvbf, DP);
  logits_k<<<dim3(N_Q * WAY), 256, 0, stream>>>(DP, out);
}

// Round 10
// 194.499 us; speedup vs baseline: 1.2215x; 1.0074x over previous
//
#include <hip/hip_runtime.h>
#include <hip/hip_bf16.h>
#include <math.h>

// ---------------- constants ----------------
#define SEQ_LEN 8
#define D_IN 2048
#define D_OUT 1152
#define WAY 5
#define SHOT 5
#define N_SUPPORT 25
#define N_Q 100
#define N_SEQ 125
#define N_ROWS 1000        // N_SEQ * SEQ_LEN
#define T_LEN 56
#define KS_LEN 280         // SHOT * T_LEN
#define KS_PAD 288         // padded (16- and 32-multiple)
#define NCOLS 6912         // 6 * D_OUT
#define MQT 5600           // N_Q * T_LEN
#define DPC 9              // 9 col-tiles, proto dist partials

typedef __attribute__((ext_vector_type(4))) float f32x4;
typedef __attribute__((ext_vector_type(8))) short bf16x8;

__constant__ int TUP[T_LEN][3] = {
  {0,1,2},{0,1,3},{0,1,4},{0,1,5},{0,1,6},{0,1,7},{0,2,3},{0,2,4},{0,2,5},{0,2,6},
  {0,2,7},{0,3,4},{0,3,5},{0,3,6},{0,3,7},{0,4,5},{0,4,6},{0,4,7},{0,5,6},{0,5,7},
  {0,6,7},{1,2,3},{1,2,4},{1,2,5},{1,2,6},{1,2,7},{1,3,4},{1,3,5},{1,3,6},{1,3,7},
  {1,4,5},{1,4,6},{1,4,7},{1,5,6},{1,5,7},{1,6,7},{2,3,4},{2,3,5},{2,3,6},{2,3,7},
  {2,4,5},{2,4,6},{2,4,7},{2,5,6},{2,5,7},{2,6,7},{3,4,5},{3,4,6},{3,4,7},{3,5,6},
  {3,5,7},{3,6,7},{4,5,6},{4,5,7},{4,6,7},{5,6,7}
};

__device__ __forceinline__ ushort f2bf(float f) {
  union { float f; unsigned u; } v; v.f = f;
  unsigned r = v.u + 0x7FFFu + ((v.u >> 16) & 1u);   // RNE
  return (ushort)(r >> 16);
}
__device__ __forceinline__ float bf2f(ushort u) {
  union { unsigned u; float f; } v; v.u = ((unsigned)u) << 16;
  return v.f;
}
__device__ __forceinline__ void gload16(const void* g, const void* l) {
  __builtin_amdgcn_global_load_lds(
      (const __attribute__((address_space(1))) unsigned int*)g,
      (__attribute__((address_space(3))) unsigned int*)l, 16, 0, 0);
}
template<int N> __device__ __forceinline__ void vmw() {
  asm volatile("s_waitcnt vmcnt(%0)" :: "n"(N) : "memory");
}
__device__ __forceinline__ void vmw_rt(int n) {
  switch (n) {
    case 0: vmw<0>(); break;
    case 3: vmw<3>(); break;
    case 4: vmw<4>(); break;
    case 6: vmw<6>(); break;
    case 8: vmw<8>(); break;
    default: vmw<0>(); break;
  }
}

// ---------------- kernel 0: Xbf = (input + PE) as bf16 ----------------
__global__ __launch_bounds__(256) void pe_add(const float* __restrict__ sup,
                                              const float* __restrict__ que,
                                              ushort* __restrict__ X) {
  int idx = blockIdx.x * 256 + threadIdx.x;
  if (idx >= N_ROWS * D_IN) return;
  int d = idx & (D_IN - 1);
  int r = idx >> 11;
  int i = r & 7;
  int h2 = d & ~1;
  float freq = expf((float)h2 * (-9.210340371976184f / (float)D_IN)); // ln(10000)
  float ang = (float)i * freq;
  float pe = ((d & 1) ? cosf(ang) : sinf(ang)) * 0.1f;
  float src = (r < N_SUPPORT * SEQ_LEN) ? sup[idx] : que[idx - N_SUPPORT * SEQ_LEN * D_IN];
  X[idx] = f2bf(src + pe);
}

// ---------------- kernel 1: WT[b*1152+n][k] = W_b[k][n] (bf16) -----------
__global__ __launch_bounds__(256) void wtrans(const float* __restrict__ kw,
                                              const float* __restrict__ vw,
                                              ushort* __restrict__ WT) {
  __shared__ float tile[64][65];
  int bx = blockIdx.x;              // 108 n-tiles (6 b-blocks x 18)
  int by = blockIdx.y;              // 32 k-tiles
  int b = bx / 18;
  int n0 = (bx % 18) * 64;
  int k0 = by * 64;
  const float* src = ((b & 1) ? vw : kw) + (size_t)(b >> 1) * D_IN * D_OUT;
  int tid = threadIdx.x;
#pragma unroll
  for (int it = 0; it < 4; ++it) {
    int lin4 = it * 256 + tid;            // 1024 float4 total
    int kk = lin4 >> 4;
    int n4 = (lin4 & 15) * 4;
    float4 v = *(const float4*)(src + (size_t)(k0 + kk) * D_OUT + n0 + n4);
    tile[kk][n4 + 0] = v.x; tile[kk][n4 + 1] = v.y;
    tile[kk][n4 + 2] = v.z; tile[kk][n4 + 3] = v.w;
  }
  __syncthreads();
#pragma unroll
  for (int it = 0; it < 4; ++it) {
    int lin = it * 1024 + tid * 4;        // 4096 elems, 4 k per thread
    int nn = lin >> 6, kk = lin & 63;
    ushort4 o;
    o.x = f2bf(tile[kk + 0][nn]); o.y = f2bf(tile[kk + 1][nn]);
    o.z = f2bf(tile[kk + 2][nn]); o.w = f2bf(tile[kk + 3][nn]);
    *(ushort4*)&WT[((size_t)(b * D_OUT + n0 + nn)) * D_IN + k0 + kk] = o;
  }
}

// --- bt-form MFMA GEMM: DEPTH-deep pipeline + counted vmcnt + swizzles ---
// SWZ 1: proj (pad y to 112, col-panel group per XCD).
// SWZ 2: scores (pad x to 48, same-x A-slabs per XCD).
template<int EPI, int NT, int DEPTH, int SWZ>
__global__ __launch_bounds__(256) void gemm_bt(
    const ushort* __restrict__ A, const ushort* __restrict__ BT,
    float* __restrict__ C,
    int M, int N, int K, int lda, int ldb, int ldc, float alpha,
    long batchA, long batchB, long batchC) {
  constexpr int JF = NT / 32;          // col frags per wave
  constexpr int NCH = 8 + NT / 16;     // 16-row staging chunks (A + B)
  __shared__ ushort As[DEPTH][128][32];
  __shared__ ushort Bs[DEPTH][NT][32];

  int bx, by, bz;
  if constexpr (SWZ == 1) {            // 896 blocks
    int L = blockIdx.x, xcd = L & 7, s = L >> 3;
    by = (s >> 3) * 8 + xcd;           // 0..111, same-panel rows on one XCD
    if (by >= 108) return;
    bx = s & 7; bz = 0;
  } else if constexpr (SWZ == 2) {     // 720 blocks
    int L = blockIdx.x, xcd = L & 7, s = L >> 3;   // s 0..89
    bx = (s % 6) * 8 + xcd;            // same-x A-slab on one XCD
    if (bx >= 44) return;
    int g = s / 6; by = g % 3; bz = g / 3;
  } else { bx = blockIdx.x; by = blockIdx.y; bz = blockIdx.z; }

  A  += (size_t)bz * batchA;
  BT += (size_t)bz * batchB;
  C  += (size_t)bz * batchC;

  int tid = threadIdx.x;
  int wid = tid >> 6, lane = tid & 63;
  int l16 = lane & 15, lk = lane >> 4;
  int wr = wid >> 1, wc = wid & 1;
  int row0 = bx * 128, col0 = by * NT;
  int lrow = lane >> 2;
  // source k-slot pre-swizzle: LDS[row][s] holds global slot s ^ ((row>>1)&3)
  int lcol = ((lane & 3) ^ ((lane >> 3) & 3)) * 8;
  // ds_read: logical slot lk lives at LDS slot lk ^ ((l16>>1)&3)
  int rslot = (lk ^ ((l16 >> 1) & 3)) * 8;

  auto stage = [&](int buf, int t) {
    int k0 = t * 32;
    for (int c = wid; c < NCH; c += 4) {            // wave-uniform chunks
      if (c < 8) {
        int grow = row0 + c * 16 + lrow;
        grow = grow < M ? grow : M - 1;
        gload16(A + (size_t)grow * lda + k0 + lcol, &As[buf][c * 16][0]);
      } else {
        int gcol = col0 + (c - 8) * 16 + lrow;
        gcol = gcol < N ? gcol : N - 1;
        gload16(BT + (size_t)gcol * ldb + k0 + lcol, &Bs[buf][(c - 8) * 16][0]);
      }
    }
  };

  int perw = NCH / 4 + ((wid < (NCH & 3)) ? 1 : 0);   // loads per wave/stage
  f32x4 acc[4][JF] = {};
  int nk = K / 32;
#pragma unroll
  for (int i = 0; i < DEPTH - 1; ++i)
    if (i < nk) stage(i, i);
  for (int t = 0; t < nk; ++t) {
    int cur = t % DEPTH;
    int ts = t + DEPTH - 1;
    if (ts < nk) stage(ts % DEPTH, ts);
    int rem = nk - 1 - t; if (rem > DEPTH - 1) rem = DEPTH - 1;
    vmw_rt(rem * perw);
    __builtin_amdgcn_s_barrier();
    __builtin_amdgcn_sched_barrier(0);
    bf16x8 af[4], bv[JF];
#pragma unroll
    for (int m = 0; m < 4; ++m)
      af[m] = *(const bf16x8*)&As[cur][wr * 64 + m * 16 + l16][rslot];
#pragma unroll
    for (int j = 0; j < JF; ++j)
      bv[j] = *(const bf16x8*)&Bs[cur][wc * (NT / 2) + j * 16 + l16][rslot];
#pragma unroll
    for (int m = 0; m < 4; ++m)
#pragma unroll
      for (int j = 0; j < JF; ++j)
        acc[m][j] = __builtin_amdgcn_mfma_f32_16x16x32_bf16(af[m], bv[j], acc[m][j], 0, 0, 0);
    __builtin_amdgcn_sched_barrier(0);
    __builtin_amdgcn_s_barrier();
  }

#pragma unroll
  for (int m = 0; m < 4; ++m)
#pragma unroll
    for (int j = 0; j < JF; ++j) {
      int col = col0 + wc * (NT / 2) + j * 16 + l16;
#pragma unroll
      for (int r = 0; r < 4; ++r) {
        int row = row0 + wr * 64 + m * 16 + lk * 4 + r;
        if (row < M && col < N)
          C[(size_t)row * ldc + col] = (EPI == 1) ? acc[m][j][r] * alpha : acc[m][j][r];
      }
    }
}

// ------- proto: B-panel-resident, barrier-free K-loop, fused dist --------
// 2160 padded blocks; same-x sm-slabs pinned per XCD.
__global__ __launch_bounds__(256) void pv_dist(const ushort* __restrict__ SM,
                                               const ushort* __restrict__ SVT,
                                               const ushort* __restrict__ QV,
                                               float* __restrict__ DP) {
  __shared__ ushort Bs[128][296];   // +8 pad: ds_read_b128 conflict-light
  int L = blockIdx.x, xcd = L & 7, s = L >> 3;   // s 0..269
  int bx = (s % 6) * 8 + xcd;
  if (bx >= 44) return;
  int g = s / 6; int by = g % 9, bz = g / 9;
  int tid = threadIdx.x, wid = tid >> 6, lane = tid & 63;
  int l16 = lane & 15, lk = lane >> 4;
  int row0 = bx * 128, col0 = by * 128, c = bz;
  const ushort* sm = SM + (size_t)c * MQT * KS_PAD;
  const ushort* bt = SVT + ((size_t)c * D_OUT + col0) * KS_PAD;
  // panel load: 2 threads per row, 18 x 16B each (full 288-ushort row)
  {
    int r = tid >> 1, h = tid & 1;
    const ushort* srcr = bt + (size_t)r * KS_PAD + h * 144;
#pragma unroll
    for (int i = 0; i < 18; ++i) {
      uint4 v = *(const uint4*)(srcr + i * 8);
      *(uint4*)&Bs[r][h * 144 + i * 8] = v;
    }
  }
  __syncthreads();

  int ra0 = row0 + wid * 32 + l16;      if (ra0 > MQT - 1) ra0 = MQT - 1;
  int ra1 = row0 + wid * 32 + 16 + l16; if (ra1 > MQT - 1) ra1 = MQT - 1;
  const ushort* a0 = sm + (size_t)ra0 * KS_PAD + lk * 8;
  const ushort* a1 = sm + (size_t)ra1 * KS_PAD + lk * 8;

  f32x4 acc[2][8] = {};
#pragma unroll
  for (int ks = 0; ks < 9; ++ks) {
    bf16x8 af0 = *(const bf16x8*)(a0 + ks * 32);
    bf16x8 af1 = *(const bf16x8*)(a1 + ks * 32);
    bf16x8 bv[8];
#pragma unroll
    for (int j = 0; j < 8; ++j)
      bv[j] = *(const bf16x8*)&Bs[j * 16 + l16][ks * 32 + lk * 8];
#pragma unroll
    for (int j = 0; j < 8; ++j) {
      acc[0][j] = __builtin_amdgcn_mfma_f32_16x16x32_bf16(af0, bv[j], acc[0][j], 0, 0, 0);
      acc[1][j] = __builtin_amdgcn_mfma_f32_16x16x32_bf16(af1, bv[j], acc[1][j], 0, 0, 0);
    }
  }

  // fused (qv - proto)^2 partials
  float sq[2][4] = {};
#pragma unroll
  for (int m = 0; m < 2; ++m)
#pragma unroll
    for (int r = 0; r < 4; ++r) {
      int row = row0 + wid * 32 + m * 16 + lk * 4 + r;
      int rowc = row < MQT ? row : MQT - 1;
      const ushort* qvr = QV + (size_t)rowc * D_OUT + col0;
#pragma unroll
      for (int j = 0; j < 8; ++j) {
        float qvv = bf2f(qvr[j * 16 + l16]);
        float d = qvv - acc[m][j][r];
        sq[m][r] += d * d;
      }
    }
#pragma unroll
  for (int m = 0; m < 2; ++m)
#pragma unroll
    for (int r = 0; r < 4; ++r) {
      sq[m][r] += __shfl_xor(sq[m][r], 1);
      sq[m][r] += __shfl_xor(sq[m][r], 2);
      sq[m][r] += __shfl_xor(sq[m][r], 4);
      sq[m][r] += __shfl_xor(sq[m][r], 8);
    }
  if (l16 == 0) {
    float* dp = DP + (size_t)c * MQT * DPC;
#pragma unroll
    for (int m = 0; m < 2; ++m)
#pragma unroll
      for (int r = 0; r < 4; ++r) {
        int row = row0 + wid * 32 + m * 16 + lk * 4 + r;
        if (row < MQT) dp[(size_t)row * DPC + by] = sq[m][r];
      }
  }
}

// ------- kernel 2: tuple-combine + bias + LN(K), wave-per-row ------------
__global__ __launch_bounds__(256) void combine_ln(const float* __restrict__ G,
                                                  const float* __restrict__ kb,
                                                  const float* __restrict__ vb,
                                                  const float* __restrict__ lng,
                                                  const float* __restrict__ lnb,
                                                  ushort* __restrict__ skbf,
                                                  ushort* __restrict__ qkbf,
                                                  ushort* __restrict__ sv,
                                                  ushort* __restrict__ qvbf) {
  int gw = blockIdx.x * 4 + (threadIdx.x >> 6);   // 0..6999
  int lane = threadIdx.x & 63;
  int t = gw % T_LEN, n = gw / T_LEN;
  const float* g0 = G + (size_t)(n * 8 + TUP[t][0]) * NCOLS;
  const float* g1 = G + (size_t)(n * 8 + TUP[t][1]) * NCOLS + 2 * D_OUT;
  const float* g2 = G + (size_t)(n * 8 + TUP[t][2]) * NCOLS + 4 * D_OUT;
  bool isq = (n >= N_SUPPORT);
  int c = n / SHOT, s = n % SHOT;
  ushort* vout = isq ? qvbf + ((size_t)(n - N_SUPPORT) * T_LEN + t) * D_OUT
                     : sv + ((size_t)c * KS_PAD + s * T_LEN + t) * D_OUT;
  ushort* kout = isq ? qkbf + ((size_t)(n - N_SUPPORT) * T_LEN + t) * D_OUT
                     : skbf + ((size_t)c * KS_PAD + s * T_LEN + t) * D_OUT;
  float kvx[9], kvy[9], s1 = 0.f, s2 = 0.f;
#pragma unroll
  for (int i = 0; i < 9; ++i) {
    int d = i * 128 + lane * 2;
    float2 a = *(const float2*)(g0 + d);
    float2 b = *(const float2*)(g0 + D_OUT + d);
    float2 c1 = *(const float2*)(g1 + d);
    float2 c2 = *(const float2*)(g1 + D_OUT + d);
    float2 e1 = *(const float2*)(g2 + d);
    float2 e2 = *(const float2*)(g2 + D_OUT + d);
    float2 kb2 = *(const float2*)(kb + d);
    float2 vb2 = *(const float2*)(vb + d);
    float kx = a.x + c1.x + e1.x + kb2.x;
    float ky = a.y + c1.y + e1.y + kb2.y;
    float vx = b.x + c2.x + e2.x + vb2.x;
    float vy = b.y + c2.y + e2.y + vb2.y;
    kvx[i] = kx; kvy[i] = ky;
    ushort2 vv; vv.x = f2bf(vx); vv.y = f2bf(vy);
    *(ushort2*)(vout + d) = vv;
    s1 += kx + ky;
    s2 += kx * kx + ky * ky;
  }
#pragma unroll
  for (int m = 32; m > 0; m >>= 1) {
    s1 += __shfl_xor(s1, m);
    s2 += __shfl_xor(s2, m);
  }
  float mu = s1 * (1.0f / D_OUT);
  float var = s2 * (1.0f / D_OUT) - mu * mu;
  float rs = rsqrtf(var + 1e-5f);
#pragma unroll
  for (int i = 0; i < 9; ++i) {
    int d = i * 128 + lane * 2;
    float2 g2v = *(const float2*)(lng + d);
    float2 b2v = *(const float2*)(lnb + d);
    ushort2 o;
    o.x = f2bf((kvx[i] - mu) * rs * g2v.x + b2v.x);
    o.y = f2bf((kvy[i] - mu) * rs * g2v.y + b2v.y);
    *(ushort2*)(kout + d) = o;
  }
}

// ---------------- kernel 2b: svT[c][d][ks] = sv[c][ks][d], zero pad -------
__global__ __launch_bounds__(256) void svtrans(const ushort* __restrict__ sv,
                                               ushort* __restrict__ svT) {
  __shared__ ushort tile[32][65];
  int c = blockIdx.z;
  int d0 = blockIdx.x * 64;   // 18 tiles
  int k0 = blockIdx.y * 32;   // 9 tiles
  const ushort* src = sv + (size_t)c * KS_PAD * D_OUT;
  ushort* dst = svT + (size_t)c * D_OUT * KS_PAD;
  int tid = threadIdx.x;
#pragma unroll
  for (int it = 0; it < 8; ++it) {
    int lin = it * 256 + tid;
    int ks = k0 + (lin >> 6), d = d0 + (lin & 63);
    tile[lin >> 6][lin & 63] = (ks < KS_LEN) ? src[(size_t)ks * D_OUT + d] : (ushort)0;
  }
  __syncthreads();
#pragma unroll
  for (int it = 0; it < 8; ++it) {
    int lin = it * 256 + tid;
    int d = lin >> 5, ks = lin & 31;
    dst[(size_t)(d0 + d) * KS_PAD + k0 + ks] = tile[ks][d];
  }
}

// ---------------- kernel 3: softmax (fp32) + align + sm bf16 -------------
__global__ __launch_bounds__(256) void softmax_align(const float* __restrict__ S,
                                                     ushort* __restrict__ sm,
                                                     float* __restrict__ align_out) {
  __shared__ float pl[4][KS_LEN];
  int wid = threadIdx.x >> 6, lane = threadIdx.x & 63;
  int row = blockIdx.x * 4 + wid;         // 0..27999
  const float* src = S + (size_t)row * KS_PAD;
  float v[5];
  float mx = -1e30f;
#pragma unroll
  for (int j = 0; j < 5; ++j) {
    int ks = lane + j * 64;
    v[j] = (ks < KS_LEN) ? src[ks] : -1e30f;
    mx = fmaxf(mx, v[j]);
  }
#pragma unroll
  for (int m = 32; m > 0; m >>= 1) mx = fmaxf(mx, __shfl_xor(mx, m));
  float sum = 0.f;
  float p[5];
#pragma unroll
  for (int j = 0; j < 5; ++j) {
    int ks = lane + j * 64;
    p[j] = (ks < KS_LEN) ? expf(v[j] - mx) : 0.f;
    sum += p[j];
  }
#pragma unroll
  for (int m = 32; m > 0; m >>= 1) sum += __shfl_xor(sum, m);
  float inv = 1.0f / sum;
  ushort* dst = sm + (size_t)row * KS_PAD;
#pragma unroll
  for (int j = 0; j < 5; ++j) {
    int ks = lane + j * 64;
    if (ks < KS_PAD) dst[ks] = f2bf((ks < KS_LEN) ? p[j] * inv : 0.f);
  }
  int c = row / MQT;
  if (c == WAY - 1) {
#pragma unroll
    for (int j = 0; j < 5; ++j) {
      int ks = lane + j * 64;
      if (ks < KS_LEN) pl[wid][ks] = p[j] * inv;
    }
    __syncthreads();
    if (lane < T_LEN) {
      float a = 0.f;
#pragma unroll
      for (int k = 0; k < SHOT; ++k) a += pl[wid][k * T_LEN + lane];
      int qt = row - (WAY - 1) * MQT;
      align_out[(size_t)(qt / T_LEN) * (T_LEN * T_LEN) + (qt % T_LEN) * T_LEN + lane] = a;
    }
  }
}

// ---------------- kernel 4: logits -----------------------------------
__global__ __launch_bounds__(256) void logits_k(const float* __restrict__ DP,
                                                float* __restrict__ out) {
  __shared__ float red[256];
  int q = blockIdx.x / WAY, c = blockIdx.x % WAY;
  const float* base = DP + ((size_t)c * MQT + q * T_LEN) * DPC;  // 56*9=504
  int tid = threadIdx.x;
  float s = 0.f;
  for (int i = tid; i < T_LEN * DPC; i += 256) s += base[i];
  red[tid] = s;
  __syncthreads();
  for (int sft = 128; sft > 0; sft >>= 1) {
    if (tid < sft) red[tid] += red[tid + sft];
    __syncthreads();
  }
  if (tid == 0) out[blockIdx.x] = -red[0] * (1.0f / T_LEN);
}

// ---------------- launch ----------------
extern "C" void kernel_launch(void* const* d_in, const int* in_sizes, int n_in,
                              void* d_out, int out_size, void* d_ws, size_t ws_size,
                              hipStream_t stream) {
  const float* sup  = (const float*)d_in[0];
  const float* que  = (const float*)d_in[1];
  const float* k_w  = (const float*)d_in[3];
  const float* k_b  = (const float*)d_in[4];
  const float* v_w  = (const float*)d_in[5];
  const float* v_b  = (const float*)d_in[6];
  const float* ln_g = (const float*)d_in[7];
  const float* ln_b = (const float*)d_in[8];
  float* out = (float*)d_out;

  char* w = (char*)d_ws;
  // Live ranges allow heavy aliasing; footprint kept at 92.5 MB.
  ushort* Xbf  = (ushort*)(w + 0);            //  4,096,000  (dead after proj)
  ushort* WT   = (ushort*)(w + 4096000);      // 28,311,552  (dead after proj)
  float*  G    = (float*)(w + 32407552);      // 27,648,000  (dead after combine)
  ushort* sv   = (ushort*)(w + 0);            //  3,317,760  (alias Xbf; dead after svtrans)
  float*  S    = (float*)(w + 0);             // 32,256,000  (alias; dead after softmax)
  ushort* smbf = (ushort*)(w + 32407552);     // 16,128,000  (alias G)
  float*  DP   = (float*)(w + 0);             //  1,008,000  (alias S after softmax)
  ushort* qkbf = (ushort*)(w + 60055552);     // 12,902,400
  ushort* skbf = (ushort*)(w + 72957952);     //  3,317,760
  ushort* svT  = (ushort*)(w + 76275712);     //  3,317,760
  ushort* qvbf = (ushort*)(w + 79593472);     // 12,902,400 -> end 92,495,872

  const float scale = 0.02946278254943948f; // 1/sqrt(1152)

  pe_add<<<dim3(8000), 256, 0, stream>>>(sup, que, Xbf);
  wtrans<<<dim3(108, 32), 256, 0, stream>>>(k_w, v_w, WT);
  gemm_bt<0, 64, 3, 1><<<dim3(896), 256, 0, stream>>>(
      Xbf, WT, G,
      N_ROWS, NCOLS, D_IN, D_IN, D_IN, NCOLS, 1.0f, 0, 0, 0);
  combine_ln<<<dim3(1750), 256, 0, stream>>>(
      G, k_b, v_b, ln_g, ln_b, skbf, qkbf, sv, qvbf);
  svtrans<<<dim3(18, 9, WAY), 256, 0, stream>>>(sv, svT);
  gemm_bt<1, 96, 2, 2><<<dim3(720), 256, 0, stream>>>(
      qkbf, skbf, S,
      MQT, KS_PAD, D_OUT, D_OUT, D_OUT, KS_PAD, scale,
      0, (long)KS_PAD * D_OUT, (long)MQT * KS_PAD);
  softmax_align<<<dim3(7000), 256, 0, stream>>>(S, smbf, out + N_Q * WAY);
  pv_dist<<<dim3(2160), 256, 0, stream>>>(smbf, svT, qvbf, DP);
  logits_k<<<dim3(N_Q * WAY), 256, 0, stream>>>(DP, out);
}